// Round 8
// baseline (181.456 us; speedup 1.0000x reference)
//
#include <hip/hip_runtime.h>
#include <hip/hip_bf16.h>

// ConvIntrinsic: gather+barycentric -> patch-operator -> 8 rotated folds.
// Circular-correlation FFT formulation (R8, verified): 8-pt real DFT over
// the angular index on both sides; ĉ[k]=X*[k]Y[k] per bin k={0&4,1,2,3};
// inverse DFT + bias + relu + k-pair fold give the 8 rotation outputs.
//
// R17: gemm is LDS-THROUGHPUT-bound (R9: 52 KB/block-K-step = 77 B/cyc/CU
// ~ the 85 B/cyc ds ceiling; R16 at 89 B/cyc got SLOWER with occupancy
// 48% -> shared-pipe saturation, not latency). A has zero cross-wave
// reuse -> drop A from LDS. Ahat re-laid out in MFMA-FRAGMENT order:
// frag(bin, mf=n>>4, kc=k>>5) is a contiguous 1 KB block with per-lane
// slot s = 4*(row&15) + kquad, so prep's EXISTING thread mapping stores
// 128B-contiguous segments and gemm loads each A-frag as ONE fully
// coalesced 1KB global_load_dwordx4 -> VGPRs. K-interleaved layout makes
// this a pure dot-index permutation (math unchanged). gemm keeps the
// verified R9 skeleton (grid 768, 2-barrier K-step, B via gload_lds with
// the sc XOR pair, fold+epilogue byte-identical); LDS/block-K-step 52->20
// KB. prep: only PACKP addresses change; gathers/compute/w2 untouched.

#define N_PTS 6000
#define RR 5
#define AA 8
#define FF 128
#define OO 128
#define QQ 40            // R*A
#define KD2 1280         // per-bin GEMM K: 5 rho x 2 part x 128 f
#define SIG_BLOCKS 750   // 8 points per block
#define W2_BLOCKS 128    // 2 j per block
#define CCQ 0.70710678118654752f
#define RT2 1.41421356237309515f

#define AHS ((size_t)N_PTS * KD2)  // per-bin Ahat elems (= 375*40*512)
#define BHS ((size_t)512 * KD2)    // per-bin Bhat elems

typedef __bf16 bf16_t;
typedef __bf16 bf16x2 __attribute__((ext_vector_type(2)));
typedef __bf16 bf16x8 __attribute__((ext_vector_type(8)));
typedef float f32x4 __attribute__((ext_vector_type(4)));

#define GLOAD_LDS16(g, l)                                              \
  __builtin_amdgcn_global_load_lds(                                    \
      (const __attribute__((address_space(1))) void*)(g),              \
      (__attribute__((address_space(3))) void*)(l), 16, 0, 0)

// 8-point real DFT, X[k] = sum_a x[a] e^{-2pi i k a/8} (verified R8).
#define DFT8V(xx, c, X0, X4, Xr1, Xi1, Xr2, Xi2, Xr3, Xi3)             \
  {                                                                    \
    const float s0_ = xx[0][c] + xx[4][c], s1_ = xx[1][c] + xx[5][c];  \
    const float s2_ = xx[2][c] + xx[6][c], s3_ = xx[3][c] + xx[7][c];  \
    const float d0_ = xx[0][c] - xx[4][c], d1_ = xx[1][c] - xx[5][c];  \
    const float d2_ = xx[2][c] - xx[6][c], d3_ = xx[3][c] - xx[7][c];  \
    const float e_ = CCQ * (d1_ - d3_), o_ = CCQ * (d1_ + d3_);        \
    X0 = (s0_ + s2_) + (s1_ + s3_);                                    \
    X4 = (s0_ + s2_) - (s1_ + s3_);                                    \
    Xr2 = s0_ - s2_; Xi2 = s3_ - s1_;                                  \
    Xr1 = d0_ + e_;  Xi1 = -(o_ + d2_);                                \
    Xr3 = d0_ - e_;  Xi3 = d2_ - o_;                                   \
  }

// pack 4 (P,Q) part-pairs interleaved: [P0,Q0,P1,Q1,P2,Q2,P3,Q3] (16 B)
#define PACKP(dst, P, Q)                                               \
  {                                                                    \
    bf16x8 pv_;                                                        \
    pv_[0] = (bf16_t)P[0]; pv_[1] = (bf16_t)Q[0];                      \
    pv_[2] = (bf16_t)P[1]; pv_[3] = (bf16_t)Q[1];                      \
    pv_[4] = (bf16_t)P[2]; pv_[5] = (bf16_t)Q[2];                      \
    pv_[6] = (bf16_t)P[3]; pv_[7] = (bf16_t)Q[3];                      \
    *(bf16x8*)(dst) = pv_;                                             \
  }

// ------------------------------------------------------- FFT prep pass
// blocks [0,750): 8 points each; 256 thr = 8 point-slots x 32 f4-lanes.
//   bary staged to LDS; float4 gathers (16 B/lane); DFT8 in regs; 16B
//   stores into FRAGMENT layout: within-bin elem offset =
//   (mf*40 + rho*8 + (l>>2))*512 + (4*(n&15) + (l&3))*8.
//   (Thread's 16B = k rho*256+l*8..+8 = kchunk rho*8+(l>>2), ksub-quad
//   l&3, rows n&15 -> slot s = 4*row + kquad. 128B store segments.)
// blocks [750,878): Bhat (row-major, UNCHANGED layout) -> DFT -> 4 bins.
__global__ __launch_bounds__(256, 6) void prep_fft_kernel(
    const float* __restrict__ mesh, const float* __restrict__ bary,
    const float* __restrict__ kw, const float* __restrict__ interp,
    bf16_t* __restrict__ Ahat, bf16_t* __restrict__ Bhat) {
  __shared__ float sh[1920];  // sig: 8x240 bary; w2: 1600 interp
  const int bx = blockIdx.x;
  const int tid = threadIdx.x;

  if (bx < SIG_BLOCKS) {
    const int slot = tid >> 5;  // 0..7
    const int l = tid & 31;     // f = l*4
    const int n = bx * 8 + slot;
    const float* bbase = bary + (size_t)bx * 8 * (QQ * 6);
    for (int i = tid; i < 1920; i += 256) sh[i] = bbase[i];
    __syncthreads();
    const float* bp = sh + slot * 240;
    // fragment-layout base for this thread (kc contribution l>>2, slot s)
    const int mf = n >> 4, prow = n & 15;
    bf16_t* an = Ahat + ((size_t)mf * 40 + (l >> 2)) * 512 +
                 (size_t)(4 * prow + (l & 3)) * 8;
#pragma unroll
    for (int rho = 0; rho < RR; ++rho) {
      float x[8][4];
#pragma unroll
      for (int a = 0; a < 8; ++a) {
        const float* rec = bp + (rho * 8 + a) * 6;  // slot-uniform (LDS)
        const float2 p0 = *(const float2*)(rec);
        const float2 p1 = *(const float2*)(rec + 2);
        const float2 p2 = *(const float2*)(rec + 4);
        const float4 v0 =
            *(const float4*)(mesh + (size_t)((int)p0.x) * FF + l * 4);
        const float4 v1 =
            *(const float4*)(mesh + (size_t)((int)p1.x) * FF + l * 4);
        const float4 v2 =
            *(const float4*)(mesh + (size_t)((int)p2.x) * FF + l * 4);
        x[a][0] = p0.y * v0.x + p1.y * v1.x + p2.y * v2.x;
        x[a][1] = p0.y * v0.y + p1.y * v1.y + p2.y * v2.y;
        x[a][2] = p0.y * v0.z + p1.y * v1.z + p2.y * v2.z;
        x[a][3] = p0.y * v0.w + p1.y * v1.w + p2.y * v2.w;
      }
      float X0[4], X4[4], Xr1[4], Xi1[4], Xr2[4], Xi2[4], Xr3[4], Xi3[4];
#pragma unroll
      for (int c = 0; c < 4; ++c)
        DFT8V(x, c, X0[c], X4[c], Xr1[c], Xi1[c], Xr2[c], Xi2[c], Xr3[c],
              Xi3[c]);
      // fragment layout: rho advances kc by 8 -> +8*512 elems
      bf16_t* dst = an + (size_t)rho * 4096;
      PACKP(dst, X0, X4);              // bin0: part0=Z0-src, part1=Z4-src
      PACKP(dst + AHS, Xr1, Xi1);      // bins 1-3: (Re, Im)
      PACKP(dst + 2 * AHS, Xr2, Xi2);
      PACKP(dst + 3 * AHS, Xr3, Xi3);
    }
  } else {
    // ---- B side: two j columns per block (128 threads each).
    const int j = (bx - SIG_BLOCKS) * 2 + (tid >> 7);  // 0..255
    const int f = tid & 127;
    for (int i = tid; i < RR * AA * QQ; i += 256) sh[i] = interp[i];
    __syncthreads();
    const int o = (j >> 1) & 127;
    const int k = j & 1;
    float acc[QQ];
#pragma unroll
    for (int q = 0; q < QQ; ++q) acc[q] = 0.f;
    for (int r = 0; r < RR; ++r) {
      for (int a = 0; a < AA; ++a) {
        const float kv =
            kw[((size_t)((r * AA + a) * 2 + k) * OO + o) * FF + f];
        const float4* ip = (const float4*)(sh + (r * AA + a) * QQ);
#pragma unroll
        for (int q4 = 0; q4 < QQ / 4; ++q4) {
          const float4 w4 = ip[q4];
          acc[q4 * 4 + 0] += w4.x * kv;
          acc[q4 * 4 + 1] += w4.y * kv;
          acc[q4 * 4 + 2] += w4.z * kv;
          acc[q4 * 4 + 3] += w4.w * kv;
        }
      }
    }
    // DFT over a; 1/8 normalization folded in. Interleaved K layout:
    // col j (Re-type) gets parts (p0,p1) per f; col 256+j (Im-type)
    // gets the conjugate-rotated pair. bin0: (Y0,0) / (0,Y4).
    const float SC = 0.125f;
    bf16_t* b1p = Bhat + (size_t)j * KD2;
    bf16_t* b2p = Bhat + (size_t)(256 + j) * KD2;
#pragma unroll
    for (int rho = 0; rho < RR; ++rho) {
      float xx[8][1];
#pragma unroll
      for (int a = 0; a < 8; ++a) xx[a][0] = acc[rho * 8 + a];
      float Y0, Y4, Yr1, Yi1, Yr2, Yi2, Yr3, Yi3;
      DFT8V(xx, 0, Y0, Y4, Yr1, Yi1, Yr2, Yi2, Yr3, Yi3);
      const int off = rho * 256 + f * 2;
      bf16x2 w;
      w[0] = (bf16_t)(Y0 * SC);   w[1] = (bf16_t)0.f;
      *(bf16x2*)(b1p + off) = w;
      w[0] = (bf16_t)0.f;         w[1] = (bf16_t)(Y4 * SC);
      *(bf16x2*)(b2p + off) = w;
      w[0] = (bf16_t)(Yr1 * SC);  w[1] = (bf16_t)(Yi1 * SC);
      *(bf16x2*)(b1p + BHS + off) = w;
      w[0] = (bf16_t)(Yi1 * SC);  w[1] = (bf16_t)(-Yr1 * SC);
      *(bf16x2*)(b2p + BHS + off) = w;
      w[0] = (bf16_t)(Yr2 * SC);  w[1] = (bf16_t)(Yi2 * SC);
      *(bf16x2*)(b1p + 2 * BHS + off) = w;
      w[0] = (bf16_t)(Yi2 * SC);  w[1] = (bf16_t)(-Yr2 * SC);
      *(bf16x2*)(b2p + 2 * BHS + off) = w;
      w[0] = (bf16_t)(Yr3 * SC);  w[1] = (bf16_t)(Yi3 * SC);
      *(bf16x2*)(b1p + 3 * BHS + off) = w;
      w[0] = (bf16_t)(Yi3 * SC);  w[1] = (bf16_t)(-Yr3 * SC);
      *(bf16x2*)(b2p + 3 * BHS + off) = w;
    }
  }
}

// --------------------------------------- fused GEMM + iDFT + epilogue
// Grid 768 (verified R9 mapping): xcd=L&7, t=L>>3; g=xcd+8*(t>>4),
// jt=t&15; m0=g*128. Block = 128m x 16j. B tile (32 rows: 0-15 Re,
// 16-31 Im) staged via gload_lds with the sc XOR pair (UNCHANGED).
// A: register-direct 1KB coalesced fragment loads (lane slot
// s = 4*tl + quad), issued between the same two barriers so the bar2
// vmcnt(0) guarantees arrival. 8 MFMA + 4 ds_read + 4 A-loads +
// 1 gload_lds per wave per 64-K step. Fold + epilogue verified R8/R9.
__global__ __launch_bounds__(256, 3) void gemm_fused_fft_kernel(
    const bf16_t* __restrict__ Ahat, const bf16_t* __restrict__ Bhat,
    const float* __restrict__ bias, float* __restrict__ out) {
  const int L = blockIdx.x;
  const int xcd = L & 7;
  const int t = L >> 3;                // 0..95
  const int g = xcd + 8 * (t >> 4);    // 0..47
  const int jt = t & 15;
  const int m0 = g * 128;
  if (m0 >= N_PTS) return;
  const int j0 = jt * 16;

  __shared__ bf16_t Bs[32 * 64];
  const int tid = threadIdx.x;
  const int wave = tid >> 6;
  const int lane = tid & 63;
  const int quad = lane >> 4;
  const int tl = lane & 15;
  const int wm = wave * 32;
  const int srow = lane >> 3;
  const int sc = (lane & 7) ^ srow;

  // this wave's B staging chunk (8 rows of the 32-row B tile)
  const int crow = wave * 8;
  const int colbase = (crow < 16) ? (j0 + crow) : (256 + j0 + (crow - 16));
  const int gcol = colbase + srow;

  // A fragment indices: two 16-row frags per wave; clamp last (rows
  // 6000-6015 alias frag 374, masked at store like the old row-clamp).
  const int mf0 = (m0 + wm) >> 4;
  int mf1 = mf0 + 1;
  if (mf1 > 374) mf1 = 374;
  const int sA = (4 * tl + quad) * 8;  // lane slot within 512-elem frag

  // iDFT coefficients: c_rot = sum_b cf[b][rot]*ReZ_b + sf[b][rot]*ImZ_b
  // (bin0: ReZ=Z0 cf=1, ImZ=Z4 sf=(-1)^rot). Verified in R8.
  static const float CF[4][8] = {
      {1, 1, 1, 1, 1, 1, 1, 1},
      {2, RT2, 0, -RT2, -2, -RT2, 0, RT2},
      {2, 0, -2, 0, 2, 0, -2, 0},
      {2, -RT2, 0, RT2, -2, RT2, 0, -RT2}};
  static const float SF[4][8] = {
      {1, -1, 1, -1, 1, -1, 1, -1},
      {0, -RT2, -2, -RT2, 0, RT2, 2, RT2},
      {0, -2, 0, 2, 0, -2, 0, 2},
      {0, -RT2, 2, -RT2, 0, RT2, -2, RT2}};

  f32x4 oacc[8][2];
#pragma unroll
  for (int rot = 0; rot < 8; ++rot)
#pragma unroll
    for (int mm = 0; mm < 2; ++mm) oacc[rot][mm] = {0.f, 0.f, 0.f, 0.f};

#pragma unroll
  for (int b = 0; b < 4; ++b) {
    const bf16_t* Af0 =
        Ahat + (size_t)b * AHS + (size_t)mf0 * 40 * 512 + sA;
    const bf16_t* Af1 =
        Ahat + (size_t)b * AHS + (size_t)mf1 * 40 * 512 + sA;
    const bf16_t* B = Bhat + (size_t)b * BHS;
    f32x4 z[2][2];
#pragma unroll
    for (int mm = 0; mm < 2; ++mm)
#pragma unroll
      for (int cc = 0; cc < 2; ++cc) z[mm][cc] = {0.f, 0.f, 0.f, 0.f};

    for (int kk = 0; kk < KD2; kk += 64) {
      __syncthreads();
      GLOAD_LDS16(B + (size_t)gcol * KD2 + kk + sc * 8, Bs + crow * 64);
      const size_t fb = (size_t)(kk >> 5) * 512;
      const bf16x8 a00 = *(const bf16x8*)(Af0 + fb);        // ks0 rows lo
      const bf16x8 a10 = *(const bf16x8*)(Af1 + fb);        // ks0 rows hi
      const bf16x8 a01 = *(const bf16x8*)(Af0 + fb + 512);  // ks1 rows lo
      const bf16x8 a11 = *(const bf16x8*)(Af1 + fb + 512);  // ks1 rows hi
      __syncthreads();
      {
        const int ch = ((quad) ^ (tl & 7)) * 8;  // ks=0
        const bf16x8 b0 = *(const bf16x8*)(Bs + tl * 64 + ch);
        const bf16x8 b1 = *(const bf16x8*)(Bs + (16 + tl) * 64 + ch);
        z[0][0] = __builtin_amdgcn_mfma_f32_16x16x32_bf16(a00, b0, z[0][0], 0, 0, 0);
        z[0][1] = __builtin_amdgcn_mfma_f32_16x16x32_bf16(a00, b1, z[0][1], 0, 0, 0);
        z[1][0] = __builtin_amdgcn_mfma_f32_16x16x32_bf16(a10, b0, z[1][0], 0, 0, 0);
        z[1][1] = __builtin_amdgcn_mfma_f32_16x16x32_bf16(a10, b1, z[1][1], 0, 0, 0);
      }
      {
        const int ch = ((4 + quad) ^ (tl & 7)) * 8;  // ks=1
        const bf16x8 b0 = *(const bf16x8*)(Bs + tl * 64 + ch);
        const bf16x8 b1 = *(const bf16x8*)(Bs + (16 + tl) * 64 + ch);
        z[0][0] = __builtin_amdgcn_mfma_f32_16x16x32_bf16(a01, b0, z[0][0], 0, 0, 0);
        z[0][1] = __builtin_amdgcn_mfma_f32_16x16x32_bf16(a01, b1, z[0][1], 0, 0, 0);
        z[1][0] = __builtin_amdgcn_mfma_f32_16x16x32_bf16(a11, b0, z[1][0], 0, 0, 0);
        z[1][1] = __builtin_amdgcn_mfma_f32_16x16x32_bf16(a11, b1, z[1][1], 0, 0, 0);
      }
    }
    // fold this bin into the 8-rot accumulator
#pragma unroll
    for (int rot = 0; rot < 8; ++rot) {
      const float cf = CF[b][rot], sf = SF[b][rot];
#pragma unroll
      for (int mm = 0; mm < 2; ++mm)
#pragma unroll
        for (int r = 0; r < 4; ++r)
          oacc[rot][mm][r] += cf * z[mm][0][r] + sf * z[mm][1][r];
    }
  }

  // epilogue: v=relu(oacc+40*bias[k,o]); lanes (tl, tl^1)=(k0,k1) of same o
  const int j = j0 + tl;  // 0..255
  const float bb = 40.0f * bias[((j & 1) << 7) | (j >> 1)];
  const int o = j >> 1;
#pragma unroll
  for (int rot = 0; rot < 8; ++rot)
#pragma unroll
    for (int mm = 0; mm < 2; ++mm)
#pragma unroll
      for (int r = 0; r < 4; ++r) {
        const int mrow = m0 + wm + mm * 16 + quad * 4 + r;
        float v = oacc[rot][mm][r] + bb;
        v = v > 0.f ? v : 0.f;
        const float vs = v + __shfl_xor(v, 1, 64);
        if (((lane & 1) == 0) && (mrow < N_PTS))
          out[(size_t)mrow * 1024 + rot * 128 + o] = vs;
      }
}

extern "C" void kernel_launch(void* const* d_in, const int* in_sizes, int n_in,
                              void* d_out, int out_size, void* d_ws,
                              size_t ws_size, hipStream_t stream) {
  const float* mesh = (const float*)d_in[0];    // (6000,128)
  const float* bary = (const float*)d_in[1];    // (6000,5,8,3,2)
  const float* kw = (const float*)d_in[2];      // (5,8,2,128,128)
  const float* bias = (const float*)d_in[3];    // (2,128)
  const float* interp = (const float*)d_in[4];  // (5,8,40)
  float* out = (float*)d_out;                   // (6000,8,128)

  bf16_t* Ahat = (bf16_t*)d_ws;                          // 61.44 MB
  bf16_t* Bhat = (bf16_t*)((char*)d_ws + 4 * AHS * 2);   // +5.24 MB

  prep_fft_kernel<<<SIG_BLOCKS + W2_BLOCKS, 256, 0, stream>>>(
      mesh, bary, kw, interp, Ahat, Bhat);
  gemm_fused_fft_kernel<<<768, 256, 0, stream>>>(Ahat, Bhat, bias, out);
}